// Round 10
// baseline (2099.715 us; speedup 1.0000x reference)
//
#include <hip/hip_runtime.h>

typedef unsigned short u16;

#define NROW 8192

__device__ __forceinline__ float bf2f(u16 h) {
  unsigned u = ((unsigned)h) << 16;
  return __builtin_bit_cast(float, u);
}
// mode-aware load: f32 ? fp32 storage : bf16 storage (upcast)
__device__ __forceinline__ float ldf(const void* p, size_t i, int f32) {
  return f32 ? ((const float*)p)[i] : bf2f(((const u16*)p)[i]);
}
// order-preserving float->uint key for atomicMax
__device__ __forceinline__ unsigned fkey(float f) {
  unsigned b = __builtin_bit_cast(unsigned, f);
  return (b & 0x80000000u) ? ~b : (b | 0x80000000u);
}
__device__ __forceinline__ float fkeydec(unsigned k) {
  unsigned b = (k & 0x80000000u) ? (k & 0x7FFFFFFFu) : ~k;
  return __builtin_bit_cast(float, b);
}

// ---- storage-dtype detection on x (N(0,1)).
__global__ void detect3(const u16* __restrict__ xr, unsigned* __restrict__ mode) {
  __shared__ int zc, bg;
  int t = threadIdx.x;   // 256
  if (t == 0) { zc = 0; bg = 0; }
  __syncthreads();
  int zeros_even = 0; int big = 0;
  for (int i = t; i < 4096; i += 256) {
    u16 v = xr[i];
    if (!(i & 1) && v == 0) zeros_even++;
    if (fabsf(bf2f(v)) > 1e6f) big = 1;
  }
  atomicAdd(&zc, zeros_even);
  if (big) atomicOr(&bg, 1);
  __syncthreads();
  if (t == 0) *mode = (zc > 512 || bg) ? 1u : 0u;   // 1 = fp32 storage
}

// ---- adj storage detection (u32 pair pattern 0x00003F80 unique to bf16).
__global__ void detect_adj(const unsigned* __restrict__ a, unsigned* __restrict__ amode) {
  __shared__ int clo;
  int t = threadIdx.x;   // 256
  if (t == 0) clo = 0;
  __syncthreads();
  int c = 0;
  for (int i = t; i < 4096; i += 256)
    if (a[i] == 0x00003F80u) c++;
  atomicAdd(&clo, c);
  __syncthreads();
  if (t == 0) *amode = (clo > 32) ? 1u : 0u;   // 1 = bf16 storage
}

// 4 adjacency bits at element offset base (base % 4 == 0).
__device__ __forceinline__ void mask4(const void* adj, size_t base, int amode, int* aa) {
  if (amode == 0) {   // int32 or fp32 storage: one u32 per element, !=0 test
    int4 av = *(const int4*)((const int*)adj + base);
    aa[0] = av.x != 0; aa[1] = av.y != 0; aa[2] = av.z != 0; aa[3] = av.w != 0;
  } else {            // bf16 storage: one u16 per element
    ushort4 av = *(const ushort4*)((const u16*)adj + base);
    aa[0] = av.x != 0; aa[1] = av.y != 0; aa[2] = av.z != 0; aa[3] = av.w != 0;
  }
}

// C[M x N] fp32 = A[M x K] @ B[K x N]; A/B raw (mode-aware) or fp32 ws buffers.
__global__ __launch_bounds__(256) void gemm_f32(const void* __restrict__ A,
    const void* __restrict__ B, float* __restrict__ C, int K, int N,
    const unsigned* __restrict__ modep, int araw, int braw) {
  int f32a = araw ? (int)*modep : 1;
  int f32b = braw ? (int)*modep : 1;
  __shared__ float sA[16][68];
  __shared__ float sB[16][68];
  int tid = threadIdx.x;
  int rb = blockIdx.y, cb = blockIdx.x;
  int tx = tid & 15, ty = tid >> 4;
  float acc[4][4] = {};
  for (int kt = 0; kt < K; kt += 16) {
    __syncthreads();
#pragma unroll
    for (int it = 0; it < 4; ++it) {
      int idx = tid + it * 256;          // 0..1023
      int m = idx & 63, kk = idx >> 6;
      sA[kk][m] = ldf(A, (size_t)(rb * 64 + m) * K + kt + kk, f32a);
      sB[kk][m] = ldf(B, (size_t)(kt + kk) * N + cb * 64 + m, f32b);
    }
    __syncthreads();
#pragma unroll
    for (int k = 0; k < 16; ++k) {
      float4 av = *(const float4*)&sA[k][ty * 4];
      float4 bv = *(const float4*)&sB[k][tx * 4];
      float aa[4] = {av.x, av.y, av.z, av.w};
      float bb[4] = {bv.x, bv.y, bv.z, bv.w};
#pragma unroll
      for (int r = 0; r < 4; ++r)
#pragma unroll
        for (int c = 0; c < 4; ++c) acc[r][c] += aa[r] * bb[c];
    }
  }
#pragma unroll
  for (int r = 0; r < 4; ++r)
#pragma unroll
    for (int c = 0; c < 4; ++c)
      C[(size_t)(rb * 64 + ty * 4 + r) * N + cb * 64 + tx * 4 + c] = acc[r][c];
}

// s_i = Wh_i . a[:F], d_i = Wh_i . a[F:] (Wh fp32, a raw), + global Dmax.
__global__ __launch_bounds__(256) void sd_f32(const float* __restrict__ Wh,
    const void* __restrict__ a2, float* __restrict__ s, float* __restrict__ d,
    unsigned* __restrict__ cell, int F, const unsigned* __restrict__ modep) {
  int f32 = (int)*modep;
  int row = blockIdx.x * 4 + (threadIdx.x >> 6);
  int l = threadIdx.x & 63;
  float ss = 0.f, dd = 0.f;
  for (int k = l; k < F; k += 64) {
    float wv = Wh[(size_t)row * F + k];
    ss += wv * ldf(a2, k, f32);
    dd += wv * ldf(a2, F + k, f32);
  }
#pragma unroll
  for (int off = 32; off > 0; off >>= 1) {
    ss += __shfl_down(ss, off, 64);
    dd += __shfl_down(dd, off, 64);
  }
  if (l == 0) {
    s[row] = ss; d[row] = dd;
    atomicMax(cell, fkey(dd));
  }
}

// Layer-1 flash: FDIM=256, R=32 rows/block, chunk=32 j, wt staged in 16-j
// halves (LDS ~20.7KB -> 7 blocks/CU). JS j-splits, grid = 256*JS.
// Accumulates unnormalized sums into acc_g/lsum_g via atomicAdd (pre-zeroed).
template <int JS>
__global__ __launch_bounds__(256) void flash1_acc(const float* __restrict__ Wh,
    const float* __restrict__ s, const float* __restrict__ d,
    const unsigned* __restrict__ cell, const void* __restrict__ adj,
    const unsigned* __restrict__ amodep,
    float* __restrict__ acc_g, float* __restrict__ lsum_g) {
  constexpr int JLEN = NROW / JS;
  constexpr int PST = 36;               // Pt j-stride (32 rows + pad)
  __shared__ __align__(16) float wt[16 * 256];   // 16KB, one 16-j half at a time
  __shared__ __align__(16) float Pt[32 * PST];   // 4.6KB, full 32-j chunk
  int tid = threadIdx.x;
  int amode = (int)*amodep;
  int rblk = blockIdx.x / JS;
  int js   = blockIdx.x - rblk * JS;
  int r0 = rblk * 32;
  int jbase = js * JLEN;
  int fg = tid & 31, rg = tid >> 5;     // PV: 32 feat-groups x 8 row-groups (RPG=4)
  int sr = tid >> 3, sjq = (tid & 7) * 4;  // score: 32 rows x 8 j-quads
  float Dmax = fkeydec(*cell);
  float svr = s[r0 + sr];
  {
    float t = svr + Dmax;
    float Mr = fmaxf(t, 0.2f * t);      // lrelu(s_i + Dmax) >= all e[i,:]
    Dmax = Mr;                          // reuse reg: Dmax now holds M_r
  }
  float acc[4][8] = {};
  float psum = 0.f;
  const size_t arowbase = (size_t)(r0 + sr) * NROW;
  for (int j0 = jbase; j0 < jbase + JLEN; j0 += 32) {
    __syncthreads();                    // S1: prior PV2 done with Pt/wt
    // phase A: stage wt half-1 + full 32-j score phase
#pragma unroll
    for (int u = tid; u < 1024; u += 256)
      *(float4*)&wt[u * 4] = *(const float4*)&Wh[(size_t)j0 * 256 + u * 4];
    {
      int aa[4];
      mask4(adj, arowbase + j0 + sjq, amode, aa);
      float4 dv = *(const float4*)&d[j0 + sjq];
      float dd[4] = {dv.x, dv.y, dv.z, dv.w};
#pragma unroll
      for (int i2 = 0; i2 < 4; ++i2) {
        float t = svr + dd[i2];
        float e = fmaxf(t, 0.2f * t) - Dmax;     // <= 0
        float p = aa[i2] ? __expf(e) : 0.f;
        psum += p;
        Pt[(sjq + i2) * PST + sr] = p;
      }
    }
    __syncthreads();                    // S2: wt1 + Pt ready
#pragma unroll 4
    for (int j = 0; j < 16; ++j) {
      float4 p0 = *(const float4*)&Pt[j * PST + rg * 4];
      float4 w0 = *(const float4*)&wt[j * 256 + fg * 8];
      float4 w1 = *(const float4*)&wt[j * 256 + fg * 8 + 4];
      float pv[4] = {p0.x, p0.y, p0.z, p0.w};
      float wv[8] = {w0.x, w0.y, w0.z, w0.w, w1.x, w1.y, w1.z, w1.w};
#pragma unroll
      for (int rr = 0; rr < 4; ++rr)
#pragma unroll
        for (int b = 0; b < 8; ++b) acc[rr][b] += pv[rr] * wv[b];
    }
    __syncthreads();                    // S3: PV1 done with wt
#pragma unroll
    for (int u = tid; u < 1024; u += 256)
      *(float4*)&wt[u * 4] = *(const float4*)&Wh[(size_t)(j0 + 16) * 256 + u * 4];
    __syncthreads();                    // S4: wt2 ready
#pragma unroll 4
    for (int j = 16; j < 32; ++j) {
      float4 p0 = *(const float4*)&Pt[j * PST + rg * 4];
      float4 w0 = *(const float4*)&wt[(j - 16) * 256 + fg * 8];
      float4 w1 = *(const float4*)&wt[(j - 16) * 256 + fg * 8 + 4];
      float pv[4] = {p0.x, p0.y, p0.z, p0.w};
      float wv[8] = {w0.x, w0.y, w0.z, w0.w, w1.x, w1.y, w1.z, w1.w};
#pragma unroll
      for (int rr = 0; rr < 4; ++rr)
#pragma unroll
        for (int b = 0; b < 8; ++b) acc[rr][b] += pv[rr] * wv[b];
    }
  }
  // ---- lsum flush: psum -> Pt -> one atomic per row
  __syncthreads();
  Pt[tid] = psum;                       // slot tid = sr*8 + quad
  __syncthreads();
  if (tid < 32) {
    float t = 0.f;
#pragma unroll
    for (int c = 0; c < 8; ++c) t += Pt[tid * 8 + c];
    atomicAdd(&lsum_g[r0 + tid], t);
  }
  // ---- accumulator flush
#pragma unroll
  for (int rr = 0; rr < 4; ++rr)
#pragma unroll
    for (int b = 0; b < 8; ++b)
      atomicAdd(&acc_g[(size_t)(r0 + rg * 4 + rr) * 256 + fg * 8 + b], acc[rr][b]);
}

// Fused layer-2/3 flash (mu+lv share adj): FDIM=64 x2, R=32, chunk=16,
// RPG=1. LDS ~13KB -> 8 blocks/CU. grid = 256*JS.
template <int JS>
__global__ __launch_bounds__(256) void flash2_fused(const float* __restrict__ Whm,
    const float* __restrict__ Whl,
    const float* __restrict__ sm, const float* __restrict__ dm,
    const float* __restrict__ sl, const float* __restrict__ dl,
    const unsigned* __restrict__ cellm, const unsigned* __restrict__ celll,
    const void* __restrict__ adj, const unsigned* __restrict__ amodep,
    float* __restrict__ accm_g, float* __restrict__ lsm_g,
    float* __restrict__ accl_g, float* __restrict__ lsl_g) {
  constexpr int JLEN = NROW / JS;
  constexpr int PST = 36;
  __shared__ __align__(16) float wtm[16 * 64];   // 4KB
  __shared__ __align__(16) float wtl[16 * 64];   // 4KB
  __shared__ __align__(16) float Ptm[16 * PST];  // 2.3KB
  __shared__ __align__(16) float Ptl[16 * PST];  // 2.3KB
  int tid = threadIdx.x;
  int amode = (int)*amodep;
  int rblk = blockIdx.x / JS;
  int js   = blockIdx.x - rblk * JS;
  int r0 = rblk * 32;
  int jbase = js * JLEN;
  int fg = tid & 7, rg = tid >> 3;      // PV: 8 feat-groups x 32 rows (RPG=1)
  int sr = tid >> 2, sjq = (tid & 3) * 4;  // score: 32 rows x 4 j-quads (tid<128)
  float Mm = 0.f, Ml = 0.f, svm = 0.f, svl = 0.f;
  if (tid < 128) {
    float Dm = fkeydec(*cellm), Dl = fkeydec(*celll);
    svm = sm[r0 + sr]; svl = sl[r0 + sr];
    float tm = svm + Dm; Mm = fmaxf(tm, 0.2f * tm);
    float tl = svl + Dl; Ml = fmaxf(tl, 0.2f * tl);
  }
  float accm[8] = {}, accl[8] = {};
  float psm = 0.f, psl = 0.f;
  const size_t arowbase = (size_t)(r0 + sr) * NROW;
  for (int j0 = jbase; j0 < jbase + JLEN; j0 += 16) {
    __syncthreads();                    // prior PV done with wt/Pt
    // stage both wt tiles: 16x64 x2 = 512 float4, 2/thread
#pragma unroll
    for (int u = tid; u < 256; u += 256) {
      *(float4*)&wtm[u * 4] = *(const float4*)&Whm[(size_t)j0 * 64 + u * 4];
      *(float4*)&wtl[u * 4] = *(const float4*)&Whl[(size_t)j0 * 64 + u * 4];
    }
    if (tid < 128) {
      int aa[4];
      mask4(adj, arowbase + j0 + sjq, amode, aa);
      float4 dvm = *(const float4*)&dm[j0 + sjq];
      float4 dvl = *(const float4*)&dl[j0 + sjq];
      float ddm[4] = {dvm.x, dvm.y, dvm.z, dvm.w};
      float ddl[4] = {dvl.x, dvl.y, dvl.z, dvl.w};
#pragma unroll
      for (int i2 = 0; i2 < 4; ++i2) {
        float tm = svm + ddm[i2];
        float em = fmaxf(tm, 0.2f * tm) - Mm;
        float pm = aa[i2] ? __expf(em) : 0.f;
        psm += pm;
        Ptm[(sjq + i2) * PST + sr] = pm;
        float tl = svl + ddl[i2];
        float el = fmaxf(tl, 0.2f * tl) - Ml;
        float pl = aa[i2] ? __expf(el) : 0.f;
        psl += pl;
        Ptl[(sjq + i2) * PST + sr] = pl;
      }
    }
    __syncthreads();                    // wt/Pt ready
#pragma unroll 4
    for (int j = 0; j < 16; ++j) {
      float pm = Ptm[j * PST + rg];
      float pl = Ptl[j * PST + rg];
      float4 wm0 = *(const float4*)&wtm[j * 64 + fg * 8];
      float4 wm1 = *(const float4*)&wtm[j * 64 + fg * 8 + 4];
      float4 wl0 = *(const float4*)&wtl[j * 64 + fg * 8];
      float4 wl1 = *(const float4*)&wtl[j * 64 + fg * 8 + 4];
      float wvm[8] = {wm0.x, wm0.y, wm0.z, wm0.w, wm1.x, wm1.y, wm1.z, wm1.w};
      float wvl[8] = {wl0.x, wl0.y, wl0.z, wl0.w, wl1.x, wl1.y, wl1.z, wl1.w};
#pragma unroll
      for (int b = 0; b < 8; ++b) {
        accm[b] += pm * wvm[b];
        accl[b] += pl * wvl[b];
      }
    }
  }
  // ---- lsum flush (both layers)
  __syncthreads();
  if (tid < 128) { Ptm[tid] = psm; Ptl[tid] = psl; }
  __syncthreads();
  if (tid < 32) {
    float tm = 0.f, tl = 0.f;
#pragma unroll
    for (int c = 0; c < 4; ++c) { tm += Ptm[tid * 4 + c]; tl += Ptl[tid * 4 + c]; }
    atomicAdd(&lsm_g[r0 + tid], tm);
    atomicAdd(&lsl_g[r0 + tid], tl);
  }
  // ---- accumulator flush
#pragma unroll
  for (int b = 0; b < 8; ++b) {
    atomicAdd(&accm_g[(size_t)(r0 + rg) * 64 + fg * 8 + b], accm[b]);
    atomicAdd(&accl_g[(size_t)(r0 + rg) * 64 + fg * 8 + b], accl[b]);
  }
}

// h = elu(acc/lsum) fp32 (layer 1). n = 8192*256.
__global__ __launch_bounds__(256) void combine_elu(const float* __restrict__ acc_g,
    const float* __restrict__ lsum_g, float* __restrict__ h) {
  int idx = blockIdx.x * 256 + threadIdx.x;
  float x = acc_g[idx] / lsum_g[idx >> 8];
  h[idx] = (x > 0.f) ? x : (__expf(x) - 1.f);
}

// out = acc/lsum fp32, dual store (ws buffer + d_out region). n = 8192*64.
__global__ __launch_bounds__(256) void combine_div(const float* __restrict__ acc_g,
    const float* __restrict__ lsum_g, float* __restrict__ outf, float* __restrict__ outd) {
  int idx = blockIdx.x * 256 + threadIdx.x;
  float x = acc_g[idx] / lsum_g[idx >> 6];
  outf[idx] = x;
  outd[idx] = x;
}

// logits = (mu + eps*exp(0.5*logvar)) @ Wc + bc (mu/lv fp32, rest raw). fp32 out.
__global__ __launch_bounds__(256) void logits_f32(const float* __restrict__ mu,
    const float* __restrict__ lv, const void* __restrict__ eps,
    const void* __restrict__ Wc, const void* __restrict__ bcv,
    float* __restrict__ outL, const unsigned* __restrict__ modep) {
  int f32 = (int)*modep;
  __shared__ float zs[64 * 64];
  __shared__ float wcs[64 * 16];
  int tid = threadIdx.x;
  for (int i = tid; i < 1024; i += 256) wcs[i] = ldf(Wc, i, f32);
  int rl = tid >> 2, cs = (tid & 3) * 16;
  int row = blockIdx.x * 64 + rl;
  size_t rb64 = (size_t)row * 64;
  for (int c = cs; c < cs + 16; ++c)
    zs[rl * 64 + c] = mu[rb64 + c] + ldf(eps, rb64 + c, f32) * __expf(0.5f * lv[rb64 + c]);
  __syncthreads();
  for (int it = tid; it < 1024; it += 256) {
    int r = it >> 4, oc = it & 15;
    float a = ldf(bcv, oc, f32);
    for (int c = 0; c < 64; ++c) a += zs[r * 64 + c] * wcs[c * 16 + oc];
    outL[(size_t)(blockIdx.x * 64 + r) * 16 + oc] = a;
  }
}

extern "C" void kernel_launch(void* const* d_in, const int* in_sizes, int n_in,
                              void* d_out, int out_size, void* d_ws, size_t ws_size,
                              hipStream_t stream) {
  (void)out_size; (void)ws_size;
  // ---- size-based input resolution (robust to permutation; ties in dict order)
  int ix = 0, iadj = 1, ieps = 2, iW1 = 3, ia1 = 4, iWmu = 5, iamu = 6,
      iWlv = 7, ialv = 8, iWc = 9, ibc = 10;
  {
    int fmu = -1, flv = -1, fam = -1, fal = -1;
    for (int i = 0; i < n_in; ++i) {
      switch (in_sizes[i]) {
        case 67108864: iadj = i; break;
        case 4194304:  ix   = i; break;
        case 524288:   ieps = i; break;
        case 131072:   iW1  = i; break;
        case 512:      ia1  = i; break;
        case 1024:     iWc  = i; break;
        case 16:       ibc  = i; break;
        case 16384:    if (fmu < 0) fmu = i; else flv = i; break;
        case 128:      if (fam < 0) fam = i; else fal = i; break;
        default: break;
      }
    }
    if (fmu >= 0 && flv >= 0) { iWmu = fmu; iWlv = flv; }
    if (fam >= 0 && fal >= 0) { iamu = fam; ialv = fal; }
  }
  const void* adj = d_in[iadj];
  char* ws = (char*)d_ws;
  const size_t KB = 1024, MB = 1024 * 1024;
  // ---- workspace (<= 24.6 MB) ----
  float* wh1   = (float*)(ws + 0);                 // 8MB [dead after flash1]
  float* whmu  = (float*)(ws + 0);                 // 2MB [overlay]
  float* whlv  = (float*)(ws + 2 * MB);            // 2MB [overlay]
  float* muf   = (float*)(ws + 4 * MB);            // 2MB [overlay]
  float* lvf   = (float*)(ws + 6 * MB);            // 2MB [overlay]
  float* h     = (float*)(ws + 8 * MB);            // 8MB
  float* hacc  = (float*)(ws + 16 * MB);           // 8MB [dead after combine1]
  float* macc  = (float*)(ws + 16 * MB);           // 2MB [overlay, memset mid-stream]
  float* lvacc = (float*)(ws + 18 * MB);           // 2MB [overlay, memset mid-stream]
  float* lsum1 = (float*)(ws + 24 * MB);           // 32KB
  float* lsmu  = (float*)(ws + 24 * MB + 32 * KB);
  float* lslv  = (float*)(ws + 24 * MB + 64 * KB);
  float* s1    = (float*)(ws + 24 * MB + 96 * KB);
  float* d1    = (float*)(ws + 24 * MB + 128 * KB);
  float* smu   = (float*)(ws + 24 * MB + 160 * KB);
  float* dmu   = (float*)(ws + 24 * MB + 192 * KB);
  float* slv   = (float*)(ws + 24 * MB + 224 * KB);
  float* dlv   = (float*)(ws + 24 * MB + 256 * KB);
  unsigned* dmx   = (unsigned*)(ws + 24 * MB + 288 * KB);  // 4 cells
  unsigned* mode  = (unsigned*)(ws + 24 * MB + 289 * KB);
  unsigned* amode = (unsigned*)(ws + 24 * MB + 290 * KB);

  // fp32 output layout: [logits 8192*16 | mu 8192*64 | logvar 8192*64]
  float* out_logits = (float*)d_out;
  float* out_mu     = (float*)d_out + 131072;
  float* out_lv     = (float*)d_out + 655360;

  (void)hipMemsetAsync(dmx, 0, 16, stream);
  (void)hipMemsetAsync(lsum1, 0, 96 * KB, stream);        // lsum1+lsmu+lslv
  (void)hipMemsetAsync(hacc, 0, 8 * MB, stream);
  detect3<<<1, 256, 0, stream>>>((const u16*)d_in[ix], mode);
  detect_adj<<<1, 256, 0, stream>>>((const unsigned*)adj, amode);

  // layer 1: Wh1 = x @ W1 (fp32), s/d, flash (JS=8, 7 blocks/CU), combine+elu
  gemm_f32<<<dim3(4, 128), 256, 0, stream>>>(d_in[ix], d_in[iW1], wh1, 512, 256, mode, 1, 1);
  sd_f32<<<2048, 256, 0, stream>>>(wh1, d_in[ia1], s1, d1, dmx + 0, 256, mode);
  flash1_acc<8><<<2048, 256, 0, stream>>>(wh1, s1, d1, dmx + 0, adj, amode, hacc, lsum1);
  combine_elu<<<8192, 256, 0, stream>>>(hacc, lsum1, h);

  // zero layer-2/3 accumulators (overlaying dead hacc; stream-ordered)
  (void)hipMemsetAsync(macc, 0, 4 * MB, stream);          // macc + lvacc

  // layers 2/3: whmu/whlv = h @ W, s/d, fused flash (JS=16, 8 blocks/CU), combine
  gemm_f32<<<dim3(1, 128), 256, 0, stream>>>(h, d_in[iWmu], whmu, 256, 64, mode, 0, 1);
  gemm_f32<<<dim3(1, 128), 256, 0, stream>>>(h, d_in[iWlv], whlv, 256, 64, mode, 0, 1);
  sd_f32<<<2048, 256, 0, stream>>>(whmu, d_in[iamu], smu, dmu, dmx + 1, 64, mode);
  sd_f32<<<2048, 256, 0, stream>>>(whlv, d_in[ialv], slv, dlv, dmx + 2, 64, mode);
  flash2_fused<16><<<4096, 256, 0, stream>>>(whmu, whlv, smu, dmu, slv, dlv,
      dmx + 1, dmx + 2, adj, amode, macc, lsmu, lvacc, lslv);
  combine_div<<<2048, 256, 0, stream>>>(macc, lsmu, muf, out_mu);
  combine_div<<<2048, 256, 0, stream>>>(lvacc, lslv, lvf, out_lv);

  logits_f32<<<128, 256, 0, stream>>>(muf, lvf, d_in[ieps], d_in[iWc], d_in[ibc], out_logits, mode);
}